// Round 12
// baseline (6004.165 us; speedup 1.0000x reference)
//
#include <hip/hip_runtime.h>

// Persistent 2-layer LSTM, plain launch (grid=256=#CUs, 1 block/CU).
// PROVEN structure (r11, 3137us): 8 row-groups x 32 col-WGs, WG = 32 batch
// rows x 64 gate cols (16 hidden units); merged h1+h2 async staging, ONE
// group-barrier per tick; agent-scope LLC exchange; plain-fp16 B fragments
// (r9); fast exp2 transcendentals (r5/r6); EARLY-H1 ORDERING (r11's big
// win, ~5us/tick): PhaseA -> writeg1 -> sync -> ew1(h1 store) -> PhaseB ->
// writeg2 -> sync -> ew2 -> barrier. ew1 VALU + h1 drain co-schedule with
// PhaseB MFMA across pipes.
// THIS ROUND, single variable: ROWB 1040 -> 1032. r11's ROWB=1040 RAISED
// SQ_LDS_BANK_CONFLICT 10x (1.7e7 -> 1.716e8 ~= 0.54us/tick if exposed);
// r10 measured 1032 at the low level with the same access pattern. Clean
// A/B: conflicts should drop ~10x; dur drop (to ~2.9ms) iff conflicts were
// on the critical path, null (~3.14ms) iff hidden under the exchange chain.

#define WGS    256
#define NTHR   256
#define TSTEPS 512
#define HDIM   512
#define BATCH  256
#define FUT    8
#define NCOL   (TSTEPS + FUT)
#define HPLANE (BATCH * HDIM)   // one h plane (fp16 hi only)
#define FLAGSTRIDE 32           // u32s per flag line (128 B)
#define ROWB   1032             // LDS row pitch bytes (1024 + 8 pad) -- r10-measured low-conflict
#define GPITCH 67               // g-tile row pitch (floats, odd stride)
#define POLLMAX 200000u         // poll bound (~33 ms) then escape (fail fast)

typedef _Float16 half_t;
typedef _Float16 f16x8 __attribute__((ext_vector_type(8)));
typedef float    f32x4 __attribute__((ext_vector_type(4)));
typedef __attribute__((address_space(1))) const unsigned int gu32;
typedef __attribute__((address_space(3))) unsigned int su32;

struct Params {
  const float* input_t;
  const float* W_ih1; const float* b_ih1; const float* W_hh1; const float* b_hh1;
  const float* W_ih2; const float* b_ih2; const float* W_hh2; const float* b_hh2;
  const float* W_lin; const float* b_lin;
  float* out;
  unsigned* flags;     // [WGS][FLAGSTRIDE]
  float* outfeed;      // [BATCH]
  half_t* h1buf;   // [2 pp][BATCH][HDIM]
  half_t* h2buf;   // [2 pp][BATCH][HDIM]
};

// Fast exact transcendentals (validated r5/r6: absmax identical to libm).
__device__ __forceinline__ float sigm(float x) {
  const float e = __builtin_amdgcn_exp2f(-1.44269504f * x);   // e^{-x}
  return __builtin_amdgcn_rcpf(1.0f + e);
}
__device__ __forceinline__ float tanh_f(float x) {
  const float e = __builtin_amdgcn_exp2f(2.88539009f * x);    // e^{2x}
  return 1.0f - 2.0f * __builtin_amdgcn_rcpf(e + 1.0f);
}

// LLC-coherent volatile accessors (proven baseline path).
__device__ __forceinline__ f16x8 vload8(const half_t* p) {
  return *(const volatile f16x8*)p;
}
__device__ __forceinline__ void vstore2(half_t* p, half_t a, half_t b) {
  union { half_t h[2]; unsigned u; } x;
  x.h[0] = a; x.h[1] = b;
  *(volatile unsigned*)p = x.u;
}

// fp32 row -> plain fp16 fragment (8 elems); r9 proved lo-correction unneeded.
__device__ __forceinline__ f16x8 load8_f16(const float* p) {
  const float4 a = *(const float4*)p;
  const float4 b = *(const float4*)(p + 4);
  f16x8 r;
  r[0] = (half_t)a.x; r[1] = (half_t)a.y; r[2] = (half_t)a.z; r[3] = (half_t)a.w;
  r[4] = (half_t)b.x; r[5] = (half_t)b.y; r[6] = (half_t)b.z; r[7] = (half_t)b.w;
  return r;
}

// Group barrier (32 WGs sharing a row-group). Store own flag (single writer
// per 128B line); threads 0..31 poll the group's flags; volatile h stores
// are at the LLC when __syncthreads' vmcnt(0) drain completes.
__device__ __forceinline__ void groupbar(unsigned* flags, int gbase, int wg, unsigned target) {
  __syncthreads();   // s_waitcnt vmcnt(0) + s_barrier
  if (threadIdx.x == 0)
    __hip_atomic_store(&flags[wg * FLAGSTRIDE], target,
                       __ATOMIC_RELAXED, __HIP_MEMORY_SCOPE_AGENT);
  if (threadIdx.x < 32) {
    unsigned iters = 0;
    while (__hip_atomic_load(&flags[(gbase + threadIdx.x) * FLAGSTRIDE],
                             __ATOMIC_RELAXED, __HIP_MEMORY_SCOPE_AGENT) < target) {
      __builtin_amdgcn_s_sleep(1);
      if (++iters > POLLMAX) break;  // bounded failsafe: fail fast, never hang
    }
  }
  __syncthreads();
}

__global__ void __launch_bounds__(NTHR, 1) lstm_fused(Params P) {
  const int tid  = threadIdx.x;
  const int wg   = blockIdx.x;
  const int cg   = wg & 31;    // col group: hidden units cg*16 .. +15
  const int rb   = wg >> 5;    // row group: batch rows rb*32 .. +31
  const int wv   = tid >> 6;   // wave 0..3 == gate index (i,f,g,o)
  const int lane = tid & 63;
  const int m    = lane & 15;
  const int quad = lane >> 4;

  __shared__ __align__(16) char ldsA1[32 * ROWB];  // staged h1 rows (33 KB)
  __shared__ __align__(16) char ldsA2[32 * ROWB];  // staged h2 rows (33 KB)
  __shared__ float g1s[32 * GPITCH];               // L1 gate pre-acts [row][p]
  __shared__ float g2s[32 * GPITCH];               // L2 gate pre-acts
  __shared__ float in_s[32];
  __shared__ float bias1_s[64];
  __shared__ float w1x_s[64];
  __shared__ float bias2_s[64];

  if (tid < 64) {   // p = tid: gate = p>>4, ul = p&15
    const int gate = tid >> 4, ul = tid & 15;
    const int gc = gate * HDIM + cg * 16 + ul;
    bias1_s[tid] = P.b_ih1[gc] + P.b_hh1[gc];
    w1x_s[tid]   = P.W_ih1[gc];
    bias2_s[tid] = P.b_ih2[gc] + P.b_hh2[gc];
  }
  if (tid < 32) in_s[tid] = P.input_t[rb * 32 + tid];

  // Register-resident PLAIN-fp16 B fragments (48 frags = 192 VGPR).
  // mfma_f32_16x16x32_f16 B layout: lane L holds B[k=(L>>4)*8+j][n=L&15].
  f16x8 B1[16];    // W_hh1
  f16x8 B2[32];    // [0..15]=W_ih2, [16..31]=W_hh2
  {
    const int gc = wv * HDIM + cg * 16 + m;   // this lane's B column
    const float* w1r  = P.W_hh1 + (size_t)gc * HDIM;
    const float* wi2r = P.W_ih2 + (size_t)gc * HDIM;
    const float* wh2r = P.W_hh2 + (size_t)gc * HDIM;
#pragma unroll
    for (int kk = 0; kk < 16; ++kk) {
      const int k0 = kk * 32 + quad * 8;
      B1[kk]      = load8_f16(w1r + k0);
      B2[kk]      = load8_f16(wi2r + k0);
      B2[16 + kk] = load8_f16(wh2r + k0);
    }
  }
  __syncthreads();

  float c1[2] = {0.f, 0.f}, c2[2] = {0.f, 0.f};   // cell state (fp32, registers)
  const int eb  = tid >> 3;        // elementwise: batch row 0..31
  const int eu0 = (tid & 7) * 2;   // elementwise: first of 2 units (0..14)

  // Bulk async stage: 8 rows per wave per plane (1024 B per instruction).
  auto stage = [&](const half_t* hp, char* ldst) {
#pragma unroll
    for (int r = 0; r < 8; ++r) {
      const int row = wv * 8 + r;
      const half_t* g = hp + (size_t)(rb * 32 + row) * HDIM + lane * 8;
      __builtin_amdgcn_global_load_lds((gu32*)g, (su32*)(ldst + row * ROWB), 16, 0, 0x11);
    }
  };

  // Output row: WG wg handles batch row wg (row wg is inside its own group).
  auto outrow = [&](const half_t* h2p, int col) {
    if (tid < 64) {
      const f16x8 hv = vload8(h2p + (size_t)wg * HDIM + lane * 8);
      const float4 wa = *(const float4*)(P.W_lin + lane * 8);
      const float4 wb = *(const float4*)(P.W_lin + lane * 8 + 4);
      float s = (float)hv[0]*wa.x + (float)hv[1]*wa.y + (float)hv[2]*wa.z + (float)hv[3]*wa.w
              + (float)hv[4]*wb.x + (float)hv[5]*wb.y + (float)hv[6]*wb.z + (float)hv[7]*wb.w;
#pragma unroll
      for (int off = 32; off > 0; off >>= 1) s += __shfl_down(s, off);
      if (lane == 0) {
        s += P.b_lin[0];
        P.out[(size_t)wg * NCOL + col] = s;
        *(volatile float*)&P.outfeed[wg] = s;
      }
    }
  };

  auto tick = [&](bool doL1, bool doL2, bool doOUT, bool future, int outcol,
                  const half_t* h1rp, half_t* h1wp,
                  const half_t* h2rp, half_t* h2wp) {
    // Merged staging: both phases issued up front, one vmcnt(0)+barrier.
    if (doL1 | doL2) stage(h1rp, ldsA1);
    if (doL2)        stage(h2rp, ldsA2);

    if (doOUT) outrow(h2rp, outcol);   // overlaps with staging in flight

    const f32x4 z4 = {0.f, 0.f, 0.f, 0.f};
    f32x4 acc1[2] = {z4, z4};
    f32x4 acc2[2] = {z4, z4};

    __syncthreads();   // staged data resident in LDS

    // A layout: lane L holds A[m=L&15][k=(L>>4)*8+j]; row tile rt: rows rt*16+m.
    const char* a1p = ldsA1 + m * ROWB + quad * 16;
    const char* a2p = ldsA2 + m * ROWB + quad * 16;

    if (doL1 | doL2) {
#pragma unroll
      for (int kk = 0; kk < 16; ++kk) {   // Phase A: A = h1[t-1]
        const int o = kk * 64;
        const f16x8 a0 = *(const f16x8*)(a1p + o);
        const f16x8 a1 = *(const f16x8*)(a1p + 16 * ROWB + o);
        if (doL1) {
          acc1[0] = __builtin_amdgcn_mfma_f32_16x16x32_f16(a0, B1[kk], acc1[0], 0, 0, 0);
          acc1[1] = __builtin_amdgcn_mfma_f32_16x16x32_f16(a1, B1[kk], acc1[1], 0, 0, 0);
        }
        if (doL2) {
          acc2[0] = __builtin_amdgcn_mfma_f32_16x16x32_f16(a0, B2[kk], acc2[0], 0, 0, 0);
          acc2[1] = __builtin_amdgcn_mfma_f32_16x16x32_f16(a1, B2[kk], acc2[1], 0, 0, 0);
        }
      }
    }

    // Early L1 finish: write g1s, sync, elementwise + h1 store FIRST so the
    // scattered h1 stores drain under Phase B MFMAs + ew2 VALU.
    if (doL1) {
#pragma unroll
      for (int rt = 0; rt < 2; ++rt)
#pragma unroll
        for (int rg = 0; rg < 4; ++rg)
          g1s[(rt * 16 + quad * 4 + rg) * GPITCH + wv * 16 + m] = acc1[rt][rg];
    }
    __syncthreads();

    if (doL1) {
      float xb = future ? *(volatile const float*)&P.outfeed[rb * 32 + eb] : in_s[eb];
      half_t hh[2];
#pragma unroll
      for (int uu = 0; uu < 2; ++uu) {
        const int u = eu0 + uu;
        const float ai = g1s[eb * GPITCH + u]      + xb * w1x_s[u]      + bias1_s[u];
        const float af = g1s[eb * GPITCH + 16 + u] + xb * w1x_s[16 + u] + bias1_s[16 + u];
        const float ag = g1s[eb * GPITCH + 32 + u] + xb * w1x_s[32 + u] + bias1_s[32 + u];
        const float ao = g1s[eb * GPITCH + 48 + u] + xb * w1x_s[48 + u] + bias1_s[48 + u];
        const float ig = sigm(ai), fg = sigm(af), gg = tanh_f(ag), og = sigm(ao);
        const float c = fg * c1[uu] + ig * gg;
        c1[uu] = c;
        hh[uu] = (half_t)(og * tanh_f(c));
      }
      vstore2(h1wp + (size_t)(rb * 32 + eb) * HDIM + cg * 16 + eu0, hh[0], hh[1]);
    }

    if (doL2) {
#pragma unroll
      for (int kk = 0; kk < 16; ++kk) {   // Phase B: A = h2[t-2]
        const int o = kk * 64;
        const f16x8 a0 = *(const f16x8*)(a2p + o);
        const f16x8 a1 = *(const f16x8*)(a2p + 16 * ROWB + o);
        acc2[0] = __builtin_amdgcn_mfma_f32_16x16x32_f16(a0, B2[16 + kk], acc2[0], 0, 0, 0);
        acc2[1] = __builtin_amdgcn_mfma_f32_16x16x32_f16(a1, B2[16 + kk], acc2[1], 0, 0, 0);
      }
#pragma unroll
      for (int rt = 0; rt < 2; ++rt)
#pragma unroll
        for (int rg = 0; rg < 4; ++rg)
          g2s[(rt * 16 + quad * 4 + rg) * GPITCH + wv * 16 + m] = acc2[rt][rg];
    }
    __syncthreads();

    if (doL2) {
      half_t hh[2];
#pragma unroll
      for (int uu = 0; uu < 2; ++uu) {
        const int u = eu0 + uu;
        const float ai = g2s[eb * GPITCH + u]      + bias2_s[u];
        const float af = g2s[eb * GPITCH + 16 + u] + bias2_s[16 + u];
        const float ag = g2s[eb * GPITCH + 32 + u] + bias2_s[32 + u];
        const float ao = g2s[eb * GPITCH + 48 + u] + bias2_s[48 + u];
        const float ig = sigm(ai), fg = sigm(af), gg = tanh_f(ag), og = sigm(ao);
        const float c = fg * c2[uu] + ig * gg;
        c2[uu] = c;
        hh[uu] = (half_t)(og * tanh_f(c));
      }
      vstore2(h2wp + (size_t)(rb * 32 + eb) * HDIM + cg * 16 + eu0, hh[0], hh[1]);
    }
  };

  half_t* h1b0 = P.h1buf;  half_t* h1b1 = P.h1buf + HPLANE;
  half_t* h2b0 = P.h2buf;  half_t* h2b1 = P.h2buf + HPLANE;
  const int gbase = wg & ~31;

  unsigned bid = 0;
  // Main pipelined ticks: tick t = L1 step t, L2 step t-1, OUT step t-2.
  for (int t = 0; t <= TSTEPS; ++t) {
    half_t* h1r = ((t + 1) & 1) ? h1b1 : h1b0;   // h1[t-1]
    half_t* h1w = (t & 1)       ? h1b1 : h1b0;   // h1[t]
    half_t* h2r = (t & 1)       ? h2b1 : h2b0;   // h2[t-2]
    half_t* h2w = ((t + 1) & 1) ? h2b1 : h2b0;   // h2[t-1]
    tick(t < TSTEPS, t >= 1, t >= 2, false, t - 2, h1r, h1w, h2r, h2w);
    groupbar(P.flags, gbase, wg, ++bid);
  }
  // Autoregressive future steps: out feeds back => 3 phases each.
  for (int k = 0; k < FUT; ++k) {
    const int s = TSTEPS + k;
    const half_t* h2last = (((s - 1) & 1)) ? h2b1 : h2b0;  // h2[s-1]
    outrow(h2last, s - 1);
    groupbar(P.flags, gbase, wg, ++bid);
    {  // L1 future step s (x = outfeed)
      half_t* h1r = (((s - 1) & 1)) ? h1b1 : h1b0;
      half_t* h1w = ((s & 1))       ? h1b1 : h1b0;
      tick(true, false, false, true, 0, h1r, h1w, h2b0, h2b0);
      groupbar(P.flags, gbase, wg, ++bid);
    }
    {  // L2 future step s (x = h1[s], hidden = h2[s-1])
      half_t* h1r = ((s & 1))       ? h1b1 : h1b0;
      half_t* h2r = (((s - 1) & 1)) ? h2b1 : h2b0;
      half_t* h2w = ((s & 1))       ? h2b1 : h2b0;
      tick(false, true, false, false, 0, h1r, h1b0, h2r, h2w);
      groupbar(P.flags, gbase, wg, ++bid);
    }
  }
  outrow((((TSTEPS + 7) & 1)) ? h2b1 : h2b0, TSTEPS + 7);
}

extern "C" void kernel_launch(void* const* d_in, const int* in_sizes, int n_in,
                              void* d_out, int out_size, void* d_ws, size_t ws_size,
                              hipStream_t stream) {
  Params P;
  P.input_t = (const float*)d_in[0];
  // d_in[1] = y : only its shape (T) matters; T hardcoded 512
  P.W_ih1 = (const float*)d_in[2];  P.b_ih1 = (const float*)d_in[3];
  P.W_hh1 = (const float*)d_in[4];  P.b_hh1 = (const float*)d_in[5];
  P.W_ih2 = (const float*)d_in[6];  P.b_ih2 = (const float*)d_in[7];
  P.W_hh2 = (const float*)d_in[8];  P.b_hh2 = (const float*)d_in[9];
  P.W_lin = (const float*)d_in[10]; P.b_lin = (const float*)d_in[11];
  P.out   = (float*)d_out;

  char* ws = (char*)d_ws;
  P.outfeed = (float*)(ws + 256);                  // 1 KB
  P.flags   = (unsigned*)(ws + 4096);              // 32 KB
  P.h1buf   = (half_t*)(ws + 4096 + 32768);        // [2][B][H] fp16 = 512 KB
  P.h2buf   = (half_t*)(ws + 4096 + 32768 + 2 * (size_t)HPLANE * sizeof(half_t));
  const size_t need = 4096 + 32768 + 4 * (size_t)HPLANE * sizeof(half_t);  // ~1.1 MB

  (void)hipMemsetAsync(d_ws, 0, need, stream);  // zero flags+outfeed+h buffers

  // PLAIN launch: grid == 256 CUs, 1 block/CU by resources => all resident.
  lstm_fused<<<dim3(WGS), dim3(NTHR), 0, stream>>>(P);
}

// Round 13
// 3780.697 us; speedup vs baseline: 1.5881x; 1.5881x over previous
//
#include <hip/hip_runtime.h>

// Persistent 2-layer LSTM, plain launch (grid=256=#CUs, 1 block/CU).
// r12 A/B isolated the true lever: ROWB=1040 (16B-aligned LDS rows ->
// every f16x8 A-fragment read is an aligned ds_read_b128) is worth 1.9x
// (3137 vs 6004us); the bank-conflict counter is anti-correlated (benign
// 8-lane/4-bank-group pattern at the 1024B/wave throughput floor) and is
// hereby non-actionable for this access shape.
// Structure: 8 row-groups x 32 col-WGs, WG = 32 batch rows x 64 gate cols;
// plain-fp16 B frags (r9); fast exp2 transcendentals (r5/r6).
// NEW: SPLIT-FLAG pipelined ticks on the unconfounded structure (r6's idea,
// retried now that the LDS confound is gone): F1 signaled mid-tick after
// ew1 (h1[t] drained), F2 at tick end after ew2 (h2[t-1] drained).
//   A-half(t): wait F1>=t; stage h1[t-1]; PhaseA; ew1 -> h1[t]; sig F1=t+1
//   B-half(t): wait F2>=t-1; stage h2[t-2]; outrow(t-2); PhaseB; ew2 ->
//              h2[t-1]; sig F2=t
// WG x's A-half(t) overlaps peers' B-half(t-1); each rendezvous waits only
// for the matching half. Overwrite hazards (h1[t-2], h2[t-3]) covered by
// the same targets (re-derived, see waits). Future steps (8x3 phases) stay
// on a full barrier (word 8). Bounded polls (~3ms) -> never hangs.

#define WGS    256
#define NTHR   256
#define TSTEPS 512
#define HDIM   512
#define BATCH  256
#define FUT    8
#define NCOL   (TSTEPS + FUT)
#define HPLANE (BATCH * HDIM)   // one h plane (fp16 hi only)
#define FLAGSTRIDE 32           // u32s per flag line (128 B, single writer)
#define ROWB   1040             // LDS row pitch: 65*16 -> aligned b128 reads (r11/r12 A/B)
#define GPITCH 67               // g-tile row pitch (floats, odd stride)
#define POLLMAX 20000u          // poll bound (~3 ms) then escape (fail fast)
#define W_F1 0                  // flag word: A-half / h1 counter
#define W_F2 4                  // flag word: B-half / h2 counter
#define W_FB 8                  // flag word: full barrier (future steps)

typedef _Float16 half_t;
typedef _Float16 f16x8 __attribute__((ext_vector_type(8)));
typedef float    f32x4 __attribute__((ext_vector_type(4)));
typedef __attribute__((address_space(1))) const unsigned int gu32;
typedef __attribute__((address_space(3))) unsigned int su32;

struct Params {
  const float* input_t;
  const float* W_ih1; const float* b_ih1; const float* W_hh1; const float* b_hh1;
  const float* W_ih2; const float* b_ih2; const float* W_hh2; const float* b_hh2;
  const float* W_lin; const float* b_lin;
  float* out;
  unsigned* flags;     // [WGS][FLAGSTRIDE]
  float* outfeed;      // [BATCH]
  half_t* h1buf;   // [2 pp][BATCH][HDIM]
  half_t* h2buf;   // [2 pp][BATCH][HDIM]
};

// Fast exact transcendentals (validated r5/r6: absmax identical to libm).
__device__ __forceinline__ float sigm(float x) {
  const float e = __builtin_amdgcn_exp2f(-1.44269504f * x);   // e^{-x}
  return __builtin_amdgcn_rcpf(1.0f + e);
}
__device__ __forceinline__ float tanh_f(float x) {
  const float e = __builtin_amdgcn_exp2f(2.88539009f * x);    // e^{2x}
  return 1.0f - 2.0f * __builtin_amdgcn_rcpf(e + 1.0f);
}

// LLC-coherent volatile accessors (proven baseline path).
__device__ __forceinline__ f16x8 vload8(const half_t* p) {
  return *(const volatile f16x8*)p;
}
__device__ __forceinline__ void vstore2(half_t* p, half_t a, half_t b) {
  union { half_t h[2]; unsigned u; } x;
  x.h[0] = a; x.h[1] = b;
  *(volatile unsigned*)p = x.u;
}

// fp32 row -> plain fp16 fragment (8 elems); r9 proved lo-correction unneeded.
__device__ __forceinline__ f16x8 load8_f16(const float* p) {
  const float4 a = *(const float4*)p;
  const float4 b = *(const float4*)(p + 4);
  f16x8 r;
  r[0] = (half_t)a.x; r[1] = (half_t)a.y; r[2] = (half_t)a.z; r[3] = (half_t)a.w;
  r[4] = (half_t)b.x; r[5] = (half_t)b.y; r[6] = (half_t)b.z; r[7] = (half_t)b.w;
  return r;
}

// Wait: all 32 group members' flag word >= target (skip if target<=0).
__device__ __forceinline__ void wfw(unsigned* flags, int gbase, int word, int target) {
  if (target > 0) {
    if (threadIdx.x < 32) {
      unsigned* fp = &flags[(gbase + threadIdx.x) * FLAGSTRIDE + word];
      unsigned iters = 0;
      while ((int)__hip_atomic_load(fp, __ATOMIC_RELAXED, __HIP_MEMORY_SCOPE_AGENT) < target) {
        __builtin_amdgcn_s_sleep(1);
        if (++iters > POLLMAX) break;  // bounded failsafe: fail fast, never hang
      }
    }
    __syncthreads();
  }
}
// Signal: drain stores (syncthreads => vmcnt(0)) then publish counter.
__device__ __forceinline__ void sigw(unsigned* flags, int wg, int word, unsigned value) {
  __syncthreads();
  if (threadIdx.x == 0)
    __hip_atomic_store(&flags[wg * FLAGSTRIDE + word], value,
                       __ATOMIC_RELAXED, __HIP_MEMORY_SCOPE_AGENT);
}

__global__ void __launch_bounds__(NTHR, 1) lstm_fused(Params P) {
  const int tid  = threadIdx.x;
  const int wg   = blockIdx.x;
  const int cg   = wg & 31;    // col group: hidden units cg*16 .. +15
  const int rb   = wg >> 5;    // row group: batch rows rb*32 .. +31
  const int gbase = wg & ~31;
  const int wv   = tid >> 6;   // wave 0..3 == gate index (i,f,g,o)
  const int lane = tid & 63;
  const int m    = lane & 15;
  const int quad = lane >> 4;

  __shared__ __align__(16) char ldsA1[32 * ROWB];  // staged h1 rows (32.5 KB)
  __shared__ __align__(16) char ldsA2[32 * ROWB];  // staged h2 rows (32.5 KB)
  __shared__ float g1s[32 * GPITCH];               // L1 gate pre-acts [row][p]
  __shared__ float g2s[32 * GPITCH];               // L2 gate pre-acts
  __shared__ float in_s[32];
  __shared__ float bias1_s[64];
  __shared__ float w1x_s[64];
  __shared__ float bias2_s[64];

  if (tid < 64) {   // p = tid: gate = p>>4, ul = p&15
    const int gate = tid >> 4, ul = tid & 15;
    const int gc = gate * HDIM + cg * 16 + ul;
    bias1_s[tid] = P.b_ih1[gc] + P.b_hh1[gc];
    w1x_s[tid]   = P.W_ih1[gc];
    bias2_s[tid] = P.b_ih2[gc] + P.b_hh2[gc];
  }
  if (tid < 32) in_s[tid] = P.input_t[rb * 32 + tid];

  // Register-resident PLAIN-fp16 B fragments (48 frags = 192 VGPR).
  // mfma_f32_16x16x32_f16 B layout: lane L holds B[k=(L>>4)*8+j][n=L&15].
  f16x8 B1[16];    // W_hh1
  f16x8 B2[32];    // [0..15]=W_ih2, [16..31]=W_hh2
  {
    const int gc = wv * HDIM + cg * 16 + m;   // this lane's B column
    const float* w1r  = P.W_hh1 + (size_t)gc * HDIM;
    const float* wi2r = P.W_ih2 + (size_t)gc * HDIM;
    const float* wh2r = P.W_hh2 + (size_t)gc * HDIM;
#pragma unroll
    for (int kk = 0; kk < 16; ++kk) {
      const int k0 = kk * 32 + quad * 8;
      B1[kk]      = load8_f16(w1r + k0);
      B2[kk]      = load8_f16(wi2r + k0);
      B2[16 + kk] = load8_f16(wh2r + k0);
    }
  }
  __syncthreads();

  float c1[2] = {0.f, 0.f}, c2[2] = {0.f, 0.f};   // cell state (fp32, registers)
  const int eb  = tid >> 3;        // elementwise: batch row 0..31
  const int eu0 = (tid & 7) * 2;   // elementwise: first of 2 units (0..14)
  const f32x4 z4 = {0.f, 0.f, 0.f, 0.f};

  // Bulk async stage: 8 rows per wave per plane (1024 B per instruction).
  auto stage = [&](const half_t* hp, char* ldst) {
#pragma unroll
    for (int r = 0; r < 8; ++r) {
      const int row = wv * 8 + r;
      const half_t* g = hp + (size_t)(rb * 32 + row) * HDIM + lane * 8;
      __builtin_amdgcn_global_load_lds((gu32*)g, (su32*)(ldst + row * ROWB), 16, 0, 0x11);
    }
  };

  // Output row: WG wg handles batch row wg (row wg is inside its own group).
  auto outrow = [&](const half_t* h2p, int col) {
    if (tid < 64) {
      const f16x8 hv = vload8(h2p + (size_t)wg * HDIM + lane * 8);
      const float4 wa = *(const float4*)(P.W_lin + lane * 8);
      const float4 wb = *(const float4*)(P.W_lin + lane * 8 + 4);
      float s = (float)hv[0]*wa.x + (float)hv[1]*wa.y + (float)hv[2]*wa.z + (float)hv[3]*wa.w
              + (float)hv[4]*wb.x + (float)hv[5]*wb.y + (float)hv[6]*wb.z + (float)hv[7]*wb.w;
#pragma unroll
      for (int off = 32; off > 0; off >>= 1) s += __shfl_down(s, off);
      if (lane == 0) {
        s += P.b_lin[0];
        P.out[(size_t)wg * NCOL + col] = s;
        *(volatile float*)&P.outfeed[wg] = s;
      }
    }
  };

  // A layout: lane L holds A[m=L&15][k=(L>>4)*8+j]; row tile rt: rows rt*16+m.
  auto phaseA = [&](bool dA1, bool dA2, f32x4* acc1, f32x4* acc2) {
    const char* a1p = ldsA1 + m * ROWB + quad * 16;
#pragma unroll
    for (int kk = 0; kk < 16; ++kk) {
      const int o = kk * 64;
      const f16x8 a0 = *(const f16x8*)(a1p + o);
      const f16x8 a1 = *(const f16x8*)(a1p + 16 * ROWB + o);
      if (dA1) {
        acc1[0] = __builtin_amdgcn_mfma_f32_16x16x32_f16(a0, B1[kk], acc1[0], 0, 0, 0);
        acc1[1] = __builtin_amdgcn_mfma_f32_16x16x32_f16(a1, B1[kk], acc1[1], 0, 0, 0);
      }
      if (dA2) {
        acc2[0] = __builtin_amdgcn_mfma_f32_16x16x32_f16(a0, B2[kk], acc2[0], 0, 0, 0);
        acc2[1] = __builtin_amdgcn_mfma_f32_16x16x32_f16(a1, B2[kk], acc2[1], 0, 0, 0);
      }
    }
  };
  auto phaseB = [&](f32x4* acc2) {
    const char* a2p = ldsA2 + m * ROWB + quad * 16;
#pragma unroll
    for (int kk = 0; kk < 16; ++kk) {
      const int o = kk * 64;
      const f16x8 a0 = *(const f16x8*)(a2p + o);
      const f16x8 a1 = *(const f16x8*)(a2p + 16 * ROWB + o);
      acc2[0] = __builtin_amdgcn_mfma_f32_16x16x32_f16(a0, B2[16 + kk], acc2[0], 0, 0, 0);
      acc2[1] = __builtin_amdgcn_mfma_f32_16x16x32_f16(a1, B2[16 + kk], acc2[1], 0, 0, 0);
    }
  };
  // C/D layout: col = lane&15 (tile col), row = rt*16 + quad*4 + reg.
  auto writeg = [&](float* gs, f32x4* acc) {
#pragma unroll
    for (int rt = 0; rt < 2; ++rt)
#pragma unroll
      for (int rg = 0; rg < 4; ++rg)
        gs[(rt * 16 + quad * 4 + rg) * GPITCH + wv * 16 + m] = acc[rt][rg];
  };
  auto ew1 = [&](bool future, half_t* h1wp) {
    const float xb = future ? *(volatile const float*)&P.outfeed[rb * 32 + eb] : in_s[eb];
    half_t hh[2];
#pragma unroll
    for (int uu = 0; uu < 2; ++uu) {
      const int u = eu0 + uu;
      const float ai = g1s[eb * GPITCH + u]      + xb * w1x_s[u]      + bias1_s[u];
      const float af = g1s[eb * GPITCH + 16 + u] + xb * w1x_s[16 + u] + bias1_s[16 + u];
      const float ag = g1s[eb * GPITCH + 32 + u] + xb * w1x_s[32 + u] + bias1_s[32 + u];
      const float ao = g1s[eb * GPITCH + 48 + u] + xb * w1x_s[48 + u] + bias1_s[48 + u];
      const float ig = sigm(ai), fg = sigm(af), gg = tanh_f(ag), og = sigm(ao);
      const float c = fg * c1[uu] + ig * gg;
      c1[uu] = c;
      hh[uu] = (half_t)(og * tanh_f(c));
    }
    vstore2(h1wp + (size_t)(rb * 32 + eb) * HDIM + cg * 16 + eu0, hh[0], hh[1]);
  };
  auto ew2 = [&](half_t* h2wp) {
    half_t hh[2];
#pragma unroll
    for (int uu = 0; uu < 2; ++uu) {
      const int u = eu0 + uu;
      const float ai = g2s[eb * GPITCH + u]      + bias2_s[u];
      const float af = g2s[eb * GPITCH + 16 + u] + bias2_s[16 + u];
      const float ag = g2s[eb * GPITCH + 32 + u] + bias2_s[32 + u];
      const float ao = g2s[eb * GPITCH + 48 + u] + bias2_s[48 + u];
      const float ig = sigm(ai), fg = sigm(af), gg = tanh_f(ag), og = sigm(ao);
      const float c = fg * c2[uu] + ig * gg;
      c2[uu] = c;
      hh[uu] = (half_t)(og * tanh_f(c));
    }
    vstore2(h2wp + (size_t)(rb * 32 + eb) * HDIM + cg * 16 + eu0, hh[0], hh[1]);
  };

  half_t* h1b0 = P.h1buf;  half_t* h1b1 = P.h1buf + HPLANE;
  half_t* h2b0 = P.h2buf;  half_t* h2b1 = P.h2buf + HPLANE;

  // ===== Main pipelined ticks with split flags =====
  for (int t = 0; t <= TSTEPS; ++t) {
    const bool doL1 = t < TSTEPS, doL2 = t >= 1, doOUT = t >= 2;
    half_t* h1r = ((t + 1) & 1) ? h1b1 : h1b0;   // h1[t-1]
    half_t* h1w = (t & 1)       ? h1b1 : h1b0;   // h1[t]
    half_t* h2r = (t & 1)       ? h2b1 : h2b0;   // h2[t-2]
    half_t* h2w = ((t + 1) & 1) ? h2b1 : h2b0;   // h2[t-1]
    f32x4 acc1[2] = {z4, z4}, acc2[2] = {z4, z4};

    // ---- A-half: consume h1[t-1], produce h1[t] ----
    wfw(P.flags, gbase, W_F1, t);        // peers' ew1(t-1) drained (also covers
                                         // h1[t-2] overwrite: their phaseA(t-1) done)
    stage(h1r, ldsA1);
    __syncthreads();                     // staged data resident
    phaseA(doL1, doL2, acc1, acc2);
    if (doL1) writeg(g1s, acc1);
    __syncthreads();
    if (doL1) ew1(false, h1w);
    sigw(P.flags, wg, W_F1, t + 1);      // h1[t] at LLC

    // ---- B-half: consume h2[t-2], produce h2[t-1], emit out[t-2] ----
    wfw(P.flags, gbase, W_F2, t - 1);    // peers' ew2(t-1) drained (h2[t-2] ready;
                                         // h2[t-3] overwrite covered likewise)
    if (doL2) stage(h2r, ldsA2);
    if (doOUT) outrow(h2r, t - 2);       // overlaps with staging in flight
    __syncthreads();
    if (doL2) { phaseB(acc2); writeg(g2s, acc2); }
    __syncthreads();
    if (doL2) ew2(h2w);
    sigw(P.flags, wg, W_F2, t);          // h2[t-1] at LLC
  }

  // ===== Autoregressive future steps: full barrier (word W_FB) =====
  unsigned fb = 0;
  auto fullbar = [&]() {
    sigw(P.flags, wg, W_FB, ++fb);
    wfw(P.flags, gbase, W_FB, (int)fb);
  };
  fullbar();   // all main-loop work (incl. peers' ew2(512)) complete
  for (int k = 0; k < FUT; ++k) {
    const int s = TSTEPS + k;
    const half_t* h2last = ((s - 1) & 1) ? h2b1 : h2b0;  // h2[s-1]
    outrow(h2last, s - 1);
    fullbar();
    {  // L1 future step s (x = outfeed)
      half_t* h1r = ((s - 1) & 1) ? h1b1 : h1b0;
      half_t* h1w = (s & 1)       ? h1b1 : h1b0;
      f32x4 acc1[2] = {z4, z4}, accd[2] = {z4, z4};
      stage(h1r, ldsA1);
      __syncthreads();
      phaseA(true, false, acc1, accd);
      writeg(g1s, acc1);
      __syncthreads();
      ew1(true, h1w);
      fullbar();
    }
    {  // L2 future step s (x = h1[s], hidden = h2[s-1])
      half_t* h1r = (s & 1)       ? h1b1 : h1b0;
      half_t* h2r = ((s - 1) & 1) ? h2b1 : h2b0;
      half_t* h2w = (s & 1)       ? h2b1 : h2b0;
      f32x4 accd[2] = {z4, z4}, acc2[2] = {z4, z4};
      stage(h1r, ldsA1);
      stage(h2r, ldsA2);
      __syncthreads();
      phaseA(false, true, accd, acc2);
      phaseB(acc2);
      writeg(g2s, acc2);
      __syncthreads();
      ew2(h2w);
      fullbar();
    }
  }
  outrow(((TSTEPS + 7) & 1) ? h2b1 : h2b0, TSTEPS + 7);
}

extern "C" void kernel_launch(void* const* d_in, const int* in_sizes, int n_in,
                              void* d_out, int out_size, void* d_ws, size_t ws_size,
                              hipStream_t stream) {
  Params P;
  P.input_t = (const float*)d_in[0];
  // d_in[1] = y : only its shape (T) matters; T hardcoded 512
  P.W_ih1 = (const float*)d_in[2];  P.b_ih1 = (const float*)d_in[3];
  P.W_hh1 = (const float*)d_in[4];  P.b_hh1 = (const float*)d_in[5];
  P.W_ih2 = (const float*)d_in[6];  P.b_ih2 = (const float*)d_in[7];
  P.W_hh2 = (const float*)d_in[8];  P.b_hh2 = (const float*)d_in[9];
  P.W_lin = (const float*)d_in[10]; P.b_lin = (const float*)d_in[11];
  P.out   = (float*)d_out;

  char* ws = (char*)d_ws;
  P.outfeed = (float*)(ws + 256);                  // 1 KB
  P.flags   = (unsigned*)(ws + 4096);              // 32 KB (F1/F2/FB words per line)
  P.h1buf   = (half_t*)(ws + 4096 + 32768);        // [2][B][H] fp16 = 512 KB
  P.h2buf   = (half_t*)(ws + 4096 + 32768 + 2 * (size_t)HPLANE * sizeof(half_t));
  const size_t need = 4096 + 32768 + 4 * (size_t)HPLANE * sizeof(half_t);  // ~1.1 MB

  (void)hipMemsetAsync(d_ws, 0, need, stream);  // zero flags+outfeed+h buffers

  // PLAIN launch: grid == 256 CUs, 1 block/CU by resources => all resident.
  lstm_fused<<<dim3(WGS), dim3(NTHR), 0, stream>>>(P);
}

// Round 14
// 3186.275 us; speedup vs baseline: 1.8844x; 1.1866x over previous
//
#include <hip/hip_runtime.h>

// Persistent 2-layer LSTM, plain launch (grid=256=#CUs, 1 block/CU).
// CHAMPION structure (r11, 3137us): 8 row-groups x 32 col-WGs, WG = 32
// batch rows x 64 gate cols; ROWB=1040 (16B-aligned LDS rows -> aligned
// ds_read_b128, the 1.9x lever; bank-conflict counter is benign here —
// r12 A/B); plain-fp16 B frags (r9); fast exp2 transcendentals (r5/r6);
// EARLY-H1 ordering (PhaseA -> writeg1 -> sync -> ew1+h1store -> PhaseB ->
// writeg2 -> sync -> ew2 -> ONE groupbar/tick). r13 proved split-flags
// regress: signaling after ew1 forces a vmcnt(0) drain before PhaseB,
// destroying exactly this overlap.
// THIS ROUND, one surgical delta on the champion: SPLIT STAGING WAIT.
// Each wave issues 8 h1-loads then 8 h2-loads (global_load_lds, FIFO per
// wave). PhaseA needs only ldsA1, so when both planes are staged we enter
// compute via raw `s_waitcnt vmcnt(8); s_barrier` (h1 complete, h2 still
// in flight) + sched_barrier(0) fence (guide rule #18). The next
// __syncthreads (before ew1/PhaseB) drains vmcnt(0) -> ldsA2 guaranteed.
// Single-plane ticks (t=0, future-L1) keep the plain __syncthreads.
// outrow moved after writeg1 so its value-use vmcnt drain (wave 0) doesn't
// re-serialize the early barrier.

#define WGS    256
#define NTHR   256
#define TSTEPS 512
#define HDIM   512
#define BATCH  256
#define FUT    8
#define NCOL   (TSTEPS + FUT)
#define HPLANE (BATCH * HDIM)   // one h plane (fp16 hi only)
#define FLAGSTRIDE 32           // u32s per flag line (128 B)
#define ROWB   1040             // LDS row pitch: 65*16 -> aligned b128 reads (r11/r12 A/B)
#define GPITCH 67               // g-tile row pitch (floats, odd stride)
#define POLLMAX 200000u         // poll bound (~33 ms) then escape (fail fast)

typedef _Float16 half_t;
typedef _Float16 f16x8 __attribute__((ext_vector_type(8)));
typedef float    f32x4 __attribute__((ext_vector_type(4)));
typedef __attribute__((address_space(1))) const unsigned int gu32;
typedef __attribute__((address_space(3))) unsigned int su32;

struct Params {
  const float* input_t;
  const float* W_ih1; const float* b_ih1; const float* W_hh1; const float* b_hh1;
  const float* W_ih2; const float* b_ih2; const float* W_hh2; const float* b_hh2;
  const float* W_lin; const float* b_lin;
  float* out;
  unsigned* flags;     // [WGS][FLAGSTRIDE]
  float* outfeed;      // [BATCH]
  half_t* h1buf;   // [2 pp][BATCH][HDIM]
  half_t* h2buf;   // [2 pp][BATCH][HDIM]
};

// Fast exact transcendentals (validated r5/r6: absmax identical to libm).
__device__ __forceinline__ float sigm(float x) {
  const float e = __builtin_amdgcn_exp2f(-1.44269504f * x);   // e^{-x}
  return __builtin_amdgcn_rcpf(1.0f + e);
}
__device__ __forceinline__ float tanh_f(float x) {
  const float e = __builtin_amdgcn_exp2f(2.88539009f * x);    // e^{2x}
  return 1.0f - 2.0f * __builtin_amdgcn_rcpf(e + 1.0f);
}

// LLC-coherent volatile accessors (proven baseline path).
__device__ __forceinline__ f16x8 vload8(const half_t* p) {
  return *(const volatile f16x8*)p;
}
__device__ __forceinline__ void vstore2(half_t* p, half_t a, half_t b) {
  union { half_t h[2]; unsigned u; } x;
  x.h[0] = a; x.h[1] = b;
  *(volatile unsigned*)p = x.u;
}

// fp32 row -> plain fp16 fragment (8 elems); r9 proved lo-correction unneeded.
__device__ __forceinline__ f16x8 load8_f16(const float* p) {
  const float4 a = *(const float4*)p;
  const float4 b = *(const float4*)(p + 4);
  f16x8 r;
  r[0] = (half_t)a.x; r[1] = (half_t)a.y; r[2] = (half_t)a.z; r[3] = (half_t)a.w;
  r[4] = (half_t)b.x; r[5] = (half_t)b.y; r[6] = (half_t)b.z; r[7] = (half_t)b.w;
  return r;
}

// Group barrier (32 WGs sharing a row-group). Store own flag (single writer
// per 128B line); threads 0..31 poll the group's flags; volatile h stores
// are at the LLC when __syncthreads' vmcnt(0) drain completes.
__device__ __forceinline__ void groupbar(unsigned* flags, int gbase, int wg, unsigned target) {
  __syncthreads();   // s_waitcnt vmcnt(0) + s_barrier
  if (threadIdx.x == 0)
    __hip_atomic_store(&flags[wg * FLAGSTRIDE], target,
                       __ATOMIC_RELAXED, __HIP_MEMORY_SCOPE_AGENT);
  if (threadIdx.x < 32) {
    unsigned iters = 0;
    while (__hip_atomic_load(&flags[(gbase + threadIdx.x) * FLAGSTRIDE],
                             __ATOMIC_RELAXED, __HIP_MEMORY_SCOPE_AGENT) < target) {
      __builtin_amdgcn_s_sleep(1);
      if (++iters > POLLMAX) break;  // bounded failsafe: fail fast, never hang
    }
  }
  __syncthreads();
}

__global__ void __launch_bounds__(NTHR, 1) lstm_fused(Params P) {
  const int tid  = threadIdx.x;
  const int wg   = blockIdx.x;
  const int cg   = wg & 31;    // col group: hidden units cg*16 .. +15
  const int rb   = wg >> 5;    // row group: batch rows rb*32 .. +31
  const int wv   = tid >> 6;   // wave 0..3 == gate index (i,f,g,o)
  const int lane = tid & 63;
  const int m    = lane & 15;
  const int quad = lane >> 4;

  __shared__ __align__(16) char ldsA1[32 * ROWB];  // staged h1 rows (32.5 KB)
  __shared__ __align__(16) char ldsA2[32 * ROWB];  // staged h2 rows (32.5 KB)
  __shared__ float g1s[32 * GPITCH];               // L1 gate pre-acts [row][p]
  __shared__ float g2s[32 * GPITCH];               // L2 gate pre-acts
  __shared__ float in_s[32];
  __shared__ float bias1_s[64];
  __shared__ float w1x_s[64];
  __shared__ float bias2_s[64];

  if (tid < 64) {   // p = tid: gate = p>>4, ul = p&15
    const int gate = tid >> 4, ul = tid & 15;
    const int gc = gate * HDIM + cg * 16 + ul;
    bias1_s[tid] = P.b_ih1[gc] + P.b_hh1[gc];
    w1x_s[tid]   = P.W_ih1[gc];
    bias2_s[tid] = P.b_ih2[gc] + P.b_hh2[gc];
  }
  if (tid < 32) in_s[tid] = P.input_t[rb * 32 + tid];

  // Register-resident PLAIN-fp16 B fragments (48 frags = 192 VGPR).
  // mfma_f32_16x16x32_f16 B layout: lane L holds B[k=(L>>4)*8+j][n=L&15].
  f16x8 B1[16];    // W_hh1
  f16x8 B2[32];    // [0..15]=W_ih2, [16..31]=W_hh2
  {
    const int gc = wv * HDIM + cg * 16 + m;   // this lane's B column
    const float* w1r  = P.W_hh1 + (size_t)gc * HDIM;
    const float* wi2r = P.W_ih2 + (size_t)gc * HDIM;
    const float* wh2r = P.W_hh2 + (size_t)gc * HDIM;
#pragma unroll
    for (int kk = 0; kk < 16; ++kk) {
      const int k0 = kk * 32 + quad * 8;
      B1[kk]      = load8_f16(w1r + k0);
      B2[kk]      = load8_f16(wi2r + k0);
      B2[16 + kk] = load8_f16(wh2r + k0);
    }
  }
  __syncthreads();

  float c1[2] = {0.f, 0.f}, c2[2] = {0.f, 0.f};   // cell state (fp32, registers)
  const int eb  = tid >> 3;        // elementwise: batch row 0..31
  const int eu0 = (tid & 7) * 2;   // elementwise: first of 2 units (0..14)

  // Bulk async stage: 8 rows per wave per plane (1024 B per instruction).
  auto stage = [&](const half_t* hp, char* ldst) {
#pragma unroll
    for (int r = 0; r < 8; ++r) {
      const int row = wv * 8 + r;
      const half_t* g = hp + (size_t)(rb * 32 + row) * HDIM + lane * 8;
      __builtin_amdgcn_global_load_lds((gu32*)g, (su32*)(ldst + row * ROWB), 16, 0, 0x11);
    }
  };

  // Output row: WG wg handles batch row wg (row wg is inside its own group).
  auto outrow = [&](const half_t* h2p, int col) {
    if (tid < 64) {
      const f16x8 hv = vload8(h2p + (size_t)wg * HDIM + lane * 8);
      const float4 wa = *(const float4*)(P.W_lin + lane * 8);
      const float4 wb = *(const float4*)(P.W_lin + lane * 8 + 4);
      float s = (float)hv[0]*wa.x + (float)hv[1]*wa.y + (float)hv[2]*wa.z + (float)hv[3]*wa.w
              + (float)hv[4]*wb.x + (float)hv[5]*wb.y + (float)hv[6]*wb.z + (float)hv[7]*wb.w;
#pragma unroll
      for (int off = 32; off > 0; off >>= 1) s += __shfl_down(s, off);
      if (lane == 0) {
        s += P.b_lin[0];
        P.out[(size_t)wg * NCOL + col] = s;
        *(volatile float*)&P.outfeed[wg] = s;
      }
    }
  };

  auto tick = [&](bool doL1, bool doL2, bool doOUT, bool future, int outcol,
                  const half_t* h1rp, half_t* h1wp,
                  const half_t* h2rp, half_t* h2wp) {
    // Staging: h1 plane first, then h2 plane (per-wave FIFO order matters
    // for the split vmcnt wait below).
    if (doL1 | doL2) stage(h1rp, ldsA1);
    if (doL2)        stage(h2rp, ldsA2);

    const f32x4 z4 = {0.f, 0.f, 0.f, 0.f};
    f32x4 acc1[2] = {z4, z4};
    f32x4 acc2[2] = {z4, z4};

    if (doL2) {
      // Both planes staged (16 loads/wave). First 8 per wave = h1 -> a
      // vmcnt(8) barrier releases PhaseA while h2 is still in flight.
      asm volatile("s_waitcnt vmcnt(8)\n\ts_barrier" ::: "memory");
      __builtin_amdgcn_sched_barrier(0);   // rule #18: pin ds_reads below
    } else {
      __syncthreads();   // single plane: plain drain
    }

    // A layout: lane L holds A[m=L&15][k=(L>>4)*8+j]; row tile rt: rows rt*16+m.
    const char* a1p = ldsA1 + m * ROWB + quad * 16;
    const char* a2p = ldsA2 + m * ROWB + quad * 16;

    if (doL1 | doL2) {
#pragma unroll
      for (int kk = 0; kk < 16; ++kk) {   // Phase A: A = h1[t-1]
        const int o = kk * 64;
        const f16x8 a0 = *(const f16x8*)(a1p + o);
        const f16x8 a1 = *(const f16x8*)(a1p + 16 * ROWB + o);
        if (doL1) {
          acc1[0] = __builtin_amdgcn_mfma_f32_16x16x32_f16(a0, B1[kk], acc1[0], 0, 0, 0);
          acc1[1] = __builtin_amdgcn_mfma_f32_16x16x32_f16(a1, B1[kk], acc1[1], 0, 0, 0);
        }
        if (doL2) {
          acc2[0] = __builtin_amdgcn_mfma_f32_16x16x32_f16(a0, B2[kk], acc2[0], 0, 0, 0);
          acc2[1] = __builtin_amdgcn_mfma_f32_16x16x32_f16(a1, B2[kk], acc2[1], 0, 0, 0);
        }
      }
    }

    // Early L1 finish: write g1s, sync, elementwise + h1 store FIRST so the
    // scattered h1 stores drain under Phase B MFMAs + ew2 VALU.
    if (doL1) {
#pragma unroll
      for (int rt = 0; rt < 2; ++rt)
#pragma unroll
        for (int rg = 0; rg < 4; ++rg)
          g1s[(rt * 16 + quad * 4 + rg) * GPITCH + wv * 16 + m] = acc1[rt][rg];
    }
    if (doOUT) outrow(h2rp, outcol);   // after the early barrier: wave-0's
                                       // value-use vmcnt drain is harmless here
    __syncthreads();                   // vmcnt(0): ldsA2 staged; g1s visible

    if (doL1) {
      float xb = future ? *(volatile const float*)&P.outfeed[rb * 32 + eb] : in_s[eb];
      half_t hh[2];
#pragma unroll
      for (int uu = 0; uu < 2; ++uu) {
        const int u = eu0 + uu;
        const float ai = g1s[eb * GPITCH + u]      + xb * w1x_s[u]      + bias1_s[u];
        const float af = g1s[eb * GPITCH + 16 + u] + xb * w1x_s[16 + u] + bias1_s[16 + u];
        const float ag = g1s[eb * GPITCH + 32 + u] + xb * w1x_s[32 + u] + bias1_s[32 + u];
        const float ao = g1s[eb * GPITCH + 48 + u] + xb * w1x_s[48 + u] + bias1_s[48 + u];
        const float ig = sigm(ai), fg = sigm(af), gg = tanh_f(ag), og = sigm(ao);
        const float c = fg * c1[uu] + ig * gg;
        c1[uu] = c;
        hh[uu] = (half_t)(og * tanh_f(c));
      }
      vstore2(h1wp + (size_t)(rb * 32 + eb) * HDIM + cg * 16 + eu0, hh[0], hh[1]);
    }

    if (doL2) {
#pragma unroll
      for (int kk = 0; kk < 16; ++kk) {   // Phase B: A = h2[t-2]
        const int o = kk * 64;
        const f16x8 a0 = *(const f16x8*)(a2p + o);
        const f16x8 a1 = *(const f16x8*)(a2p + 16 * ROWB + o);
        acc2[0] = __builtin_amdgcn_mfma_f32_16x16x32_f16(a0, B2[16 + kk], acc2[0], 0, 0, 0);
        acc2[1] = __builtin_amdgcn_mfma_f32_16x16x32_f16(a1, B2[16 + kk], acc2[1], 0, 0, 0);
      }
#pragma unroll
      for (int rt = 0; rt < 2; ++rt)
#pragma unroll
        for (int rg = 0; rg < 4; ++rg)
          g2s[(rt * 16 + quad * 4 + rg) * GPITCH + wv * 16 + m] = acc2[rt][rg];
    }
    __syncthreads();

    if (doL2) {
      half_t hh[2];
#pragma unroll
      for (int uu = 0; uu < 2; ++uu) {
        const int u = eu0 + uu;
        const float ai = g2s[eb * GPITCH + u]      + bias2_s[u];
        const float af = g2s[eb * GPITCH + 16 + u] + bias2_s[16 + u];
        const float ag = g2s[eb * GPITCH + 32 + u] + bias2_s[32 + u];
        const float ao = g2s[eb * GPITCH + 48 + u] + bias2_s[48 + u];
        const float ig = sigm(ai), fg = sigm(af), gg = tanh_f(ag), og = sigm(ao);
        const float c = fg * c2[uu] + ig * gg;
        c2[uu] = c;
        hh[uu] = (half_t)(og * tanh_f(c));
      }
      vstore2(h2wp + (size_t)(rb * 32 + eb) * HDIM + cg * 16 + eu0, hh[0], hh[1]);
    }
  };

  half_t* h1b0 = P.h1buf;  half_t* h1b1 = P.h1buf + HPLANE;
  half_t* h2b0 = P.h2buf;  half_t* h2b1 = P.h2buf + HPLANE;
  const int gbase = wg & ~31;

  unsigned bid = 0;
  // Main pipelined ticks: tick t = L1 step t, L2 step t-1, OUT step t-2.
  for (int t = 0; t <= TSTEPS; ++t) {
    half_t* h1r = ((t + 1) & 1) ? h1b1 : h1b0;   // h1[t-1]
    half_t* h1w = (t & 1)       ? h1b1 : h1b0;   // h1[t]
    half_t* h2r = (t & 1)       ? h2b1 : h2b0;   // h2[t-2]
    half_t* h2w = ((t + 1) & 1) ? h2b1 : h2b0;   // h2[t-1]
    tick(t < TSTEPS, t >= 1, t >= 2, false, t - 2, h1r, h1w, h2r, h2w);
    groupbar(P.flags, gbase, wg, ++bid);
  }
  // Autoregressive future steps: out feeds back => 3 phases each.
  for (int k = 0; k < FUT; ++k) {
    const int s = TSTEPS + k;
    const half_t* h2last = (((s - 1) & 1)) ? h2b1 : h2b0;  // h2[s-1]
    outrow(h2last, s - 1);
    groupbar(P.flags, gbase, wg, ++bid);
    {  // L1 future step s (x = outfeed)
      half_t* h1r = (((s - 1) & 1)) ? h1b1 : h1b0;
      half_t* h1w = ((s & 1))       ? h1b1 : h1b0;
      tick(true, false, false, true, 0, h1r, h1w, h2b0, h2b0);
      groupbar(P.flags, gbase, wg, ++bid);
    }
    {  // L2 future step s (x = h1[s], hidden = h2[s-1])
      half_t* h1r = ((s & 1))       ? h1b1 : h1b0;
      half_t* h2r = (((s - 1) & 1)) ? h2b1 : h2b0;
      half_t* h2w = ((s & 1))       ? h2b1 : h2b0;
      tick(false, true, false, false, 0, h1r, h1b0, h2r, h2w);
      groupbar(P.flags, gbase, wg, ++bid);
    }
  }
  outrow((((TSTEPS + 7) & 1)) ? h2b1 : h2b0, TSTEPS + 7);
}

extern "C" void kernel_launch(void* const* d_in, const int* in_sizes, int n_in,
                              void* d_out, int out_size, void* d_ws, size_t ws_size,
                              hipStream_t stream) {
  Params P;
  P.input_t = (const float*)d_in[0];
  // d_in[1] = y : only its shape (T) matters; T hardcoded 512
  P.W_ih1 = (const float*)d_in[2];  P.b_ih1 = (const float*)d_in[3];
  P.W_hh1 = (const float*)d_in[4];  P.b_hh1 = (const float*)d_in[5];
  P.W_ih2 = (const float*)d_in[6];  P.b_ih2 = (const float*)d_in[7];
  P.W_hh2 = (const float*)d_in[8];  P.b_hh2 = (const float*)d_in[9];
  P.W_lin = (const float*)d_in[10]; P.b_lin = (const float*)d_in[11];
  P.out   = (float*)d_out;

  char* ws = (char*)d_ws;
  P.outfeed = (float*)(ws + 256);                  // 1 KB
  P.flags   = (unsigned*)(ws + 4096);              // 32 KB
  P.h1buf   = (half_t*)(ws + 4096 + 32768);        // [2][B][H] fp16 = 512 KB
  P.h2buf   = (half_t*)(ws + 4096 + 32768 + 2 * (size_t)HPLANE * sizeof(half_t));
  const size_t need = 4096 + 32768 + 4 * (size_t)HPLANE * sizeof(half_t);  // ~1.1 MB

  (void)hipMemsetAsync(d_ws, 0, need, stream);  // zero flags+outfeed+h buffers

  // PLAIN launch: grid == 256 CUs, 1 block/CU by resources => all resident.
  lstm_fused<<<dim3(WGS), dim3(NTHR), 0, stream>>>(P);
}